// Round 4
// baseline (232.946 us; speedup 1.0000x reference)
//
#include <hip/hip_runtime.h>

#define D 64
#define NK 1024
#define QTOTAL 65536
#define NELEM (QTOTAL * D)      // 4194304
#define LOSS_OFF 4194304
#define IDX_OFF  4194305

typedef float f32x16 __attribute__((ext_vector_type(16)));

// 16 consecutive code elements (SGPR-resident, wave-uniform) against this
// lane's query; 4 independent FMA chains (dims ≡ j mod 4 -> chain j).
#define DO_CHUNK(B, K) \
    a0 = fmaf(B[0],  xA[4*K+0].x, a0); a1 = fmaf(B[1],  xA[4*K+0].y, a1); \
    a2 = fmaf(B[2],  xA[4*K+0].z, a2); a3 = fmaf(B[3],  xA[4*K+0].w, a3); \
    a0 = fmaf(B[4],  xA[4*K+1].x, a0); a1 = fmaf(B[5],  xA[4*K+1].y, a1); \
    a2 = fmaf(B[6],  xA[4*K+1].z, a2); a3 = fmaf(B[7],  xA[4*K+1].w, a3); \
    a0 = fmaf(B[8],  xA[4*K+2].x, a0); a1 = fmaf(B[9],  xA[4*K+2].y, a1); \
    a2 = fmaf(B[10], xA[4*K+2].z, a2); a3 = fmaf(B[11], xA[4*K+2].w, a3); \
    a0 = fmaf(B[12], xA[4*K+3].x, a0); a1 = fmaf(B[13], xA[4*K+3].y, a1); \
    a2 = fmaf(B[14], xA[4*K+3].z, a2); a3 = fmaf(B[15], xA[4*K+3].w, a3);

// 1024 blocks x 256 threads, 4 blocks/CU -> 4 waves/SIMD (TLP hides the
// per-iteration SMEM wait that R3 exposed at 2 waves/SIMD). Block owns 64
// queries (1/lane); each wave owns a wave-uniform quarter of the codebook,
// streamed through SGPRs via self-contained s_load_dwordx16+waitcnt asm
// (no in-flight SGPRs ever cross an asm boundary). |e|^2 computed per-block
// into LDS (L2-hot reads); loss partial per block into d_ws.
__global__ __launch_bounds__(256, 4) void vq_main_kernel(const float* __restrict__ x,
                                                         const float* __restrict__ emb,
                                                         float* __restrict__ out,
                                                         float* __restrict__ ws) {
    __shared__ float e2l[NK];        // 4 KB, broadcast-read (wave-uniform addr)
    __shared__ float sm_s[256];
    __shared__ int   sm_c[256];

    const int tid = threadIdx.x;
    const int l   = tid & 63;
    const int w   = tid >> 6;
    const int qbase = blockIdx.x * 64;
    const int q   = qbase + l;       // all 4 waves process the same 64 queries

    // Per-block |e|^2 for all 1024 codes (4 rows/thread), same accumulation
    // order as the R3 e2 kernel (deterministic, identical across blocks).
    {
#pragma unroll
        for (int c = 0; c < 4; ++c) {
            int row = c * 256 + tid;
            const float4* e4 = (const float4*)(emb + (long)row * D);
            float s = 0.f;
#pragma unroll
            for (int i = 0; i < D / 4; ++i) {
                float4 v = e4[i];
                s += v.x * v.x + v.y * v.y + v.z * v.z + v.w * v.w;
            }
            e2l[row] = s;
        }
    }

    // Query resident in VGPRs (64 VGPRs).
    float4 xA[16];
    const float4* xp = (const float4*)(x + (long)q * D);
#pragma unroll
    for (int i = 0; i < 16; ++i) xA[i] = xp[i];
    __syncthreads();

    const int code0 = __builtin_amdgcn_readfirstlane(w << 8);  // wave's first code
    const float* ep0 = emb + (long)code0 * D;

    float bestA = 3.4e38f;
    int idxA = 0;

#pragma unroll 1
    for (int g = 0; g < 256; ++g) {
        const float* ep = ep0 + g * D;   // wave-uniform -> SGPR pair
        f32x16 b0, b1, b2, b3;
        asm volatile(
            "s_load_dwordx16 %0, %4, 0x0\n\t"
            "s_load_dwordx16 %1, %4, 0x40\n\t"
            "s_load_dwordx16 %2, %4, 0x80\n\t"
            "s_load_dwordx16 %3, %4, 0xC0\n\t"
            "s_waitcnt lgkmcnt(0)"
            : "=s"(b0), "=s"(b1), "=s"(b2), "=s"(b3)
            : "s"(ep));

        float a0 = 0.f, a1 = 0.f, a2 = 0.f, a3 = 0.f;
        DO_CHUNK(b0, 0)
        DO_CHUNK(b1, 1)
        DO_CHUNK(b2, 2)
        DO_CHUNK(b3, 3)

        float dotA = (a0 + a1) + (a2 + a3);
        float e2c = e2l[code0 + g];           // uniform ds_read_b32: broadcast
        float sA = 0.5f * e2c - dotA;         // same surrogate as R3
        int code = code0 + g;
        bool ltA = sA < bestA; bestA = ltA ? sA : bestA; idxA = ltA ? code : idxA;
    }

    // Cross-wave merge: ascending wave == ascending code range, strict < keeps
    // the first minimum (numpy argmin tie-break preserved).
    sm_s[w * 64 + l] = bestA;  sm_c[w * 64 + l] = idxA;
    __syncthreads();

    if (tid < 64) {
        float bs = sm_s[tid];
        int   bc = sm_c[tid];
#pragma unroll
        for (int wv = 1; wv < 4; ++wv) {
            float s = sm_s[wv * 64 + tid];
            int   c = sm_c[wv * 64 + tid];
            if (s < bs) { bs = s; bc = c; }
        }
        const int qq = qbase + tid;
        out[IDX_OFF + qq] = (float)bc;

        const float4* eb = (const float4*)(emb + (long)bc * D);
        const float4* xq = (const float4*)(x + (long)qq * D);
        float4* oq = (float4*)(out + (long)qq * D);
        float lsum = 0.f;
#pragma unroll
        for (int i = 0; i < 16; ++i) {
            float4 e = eb[i];
            float4 xx = xq[i];
            oq[i] = e;
            float dx = e.x - xx.x, dy = e.y - xx.y, dz = e.z - xx.z, dw = e.w - xx.w;
            lsum += dx * dx + dy * dy + dz * dz + dw * dw;
        }
        // tid<64 == wave 0, fully active -> full 64-lane shuffle reduce
#pragma unroll
        for (int o = 32; o > 0; o >>= 1)
            lsum += __shfl_down(lsum, o, 64);
        if (tid == 0)
            ws[blockIdx.x] = lsum;            // raw partial; scaled in tail kernel
    }
}

// Tail: reduce 1024 per-block partials -> loss. One wave.
__global__ __launch_bounds__(64) void vq_loss_kernel(const float* __restrict__ ws,
                                                     float* __restrict__ out) {
    const int l = threadIdx.x;
    float s = 0.f;
#pragma unroll
    for (int i = 0; i < 16; ++i) s += ws[l + 64 * i];
#pragma unroll
    for (int o = 32; o > 0; o >>= 1) s += __shfl_down(s, o, 64);
    if (l == 0) out[LOSS_OFF] = s * (0.25f / (float)NELEM);
}

extern "C" void kernel_launch(void* const* d_in, const int* in_sizes, int n_in,
                              void* d_out, int out_size, void* d_ws, size_t ws_size,
                              hipStream_t stream) {
    const float* inputs = (const float*)d_in[0];      // [65536, 64]
    const float* emb    = (const float*)d_in[1];      // [1024, 64]
    float* out = (float*)d_out;
    float* ws  = (float*)d_ws;                        // 1024 partial-loss floats

    vq_main_kernel<<<QTOTAL / 64, 256, 0, stream>>>(inputs, emb, out, ws);
    vq_loss_kernel<<<1, 64, 0, stream>>>(ws, out);
}

// Round 5
// 218.830 us; speedup vs baseline: 1.0645x; 1.0645x over previous
//
#include <hip/hip_runtime.h>

#define D 64
#define NK 1024
#define QTOTAL 65536
#define NELEM (QTOTAL * D)      // 4194304
#define LOSS_OFF 4194304
#define IDX_OFF  4194305

typedef float f32x16 __attribute__((ext_vector_type(16)));
typedef float f32x4v __attribute__((ext_vector_type(4)));

// 16 consecutive code elements (SGPR-resident, wave-uniform) against both
// queries; 4 independent FMA chains per query (dim ≡ j mod 4 -> chain j).
#define DO_CHUNK(B, K) \
    aA0 = fmaf(B[0],  xA[4*K+0].x, aA0); aA1 = fmaf(B[1],  xA[4*K+0].y, aA1); \
    aA2 = fmaf(B[2],  xA[4*K+0].z, aA2); aA3 = fmaf(B[3],  xA[4*K+0].w, aA3); \
    aA0 = fmaf(B[4],  xA[4*K+1].x, aA0); aA1 = fmaf(B[5],  xA[4*K+1].y, aA1); \
    aA2 = fmaf(B[6],  xA[4*K+1].z, aA2); aA3 = fmaf(B[7],  xA[4*K+1].w, aA3); \
    aA0 = fmaf(B[8],  xA[4*K+2].x, aA0); aA1 = fmaf(B[9],  xA[4*K+2].y, aA1); \
    aA2 = fmaf(B[10], xA[4*K+2].z, aA2); aA3 = fmaf(B[11], xA[4*K+2].w, aA3); \
    aA0 = fmaf(B[12], xA[4*K+3].x, aA0); aA1 = fmaf(B[13], xA[4*K+3].y, aA1); \
    aA2 = fmaf(B[14], xA[4*K+3].z, aA2); aA3 = fmaf(B[15], xA[4*K+3].w, aA3); \
    aB0 = fmaf(B[0],  xB[4*K+0].x, aB0); aB1 = fmaf(B[1],  xB[4*K+0].y, aB1); \
    aB2 = fmaf(B[2],  xB[4*K+0].z, aB2); aB3 = fmaf(B[3],  xB[4*K+0].w, aB3); \
    aB0 = fmaf(B[4],  xB[4*K+1].x, aB0); aB1 = fmaf(B[5],  xB[4*K+1].y, aB1); \
    aB2 = fmaf(B[6],  xB[4*K+1].z, aB2); aB3 = fmaf(B[7],  xB[4*K+1].w, aB3); \
    aB0 = fmaf(B[8],  xB[4*K+2].x, aB0); aB1 = fmaf(B[9],  xB[4*K+2].y, aB1); \
    aB2 = fmaf(B[10], xB[4*K+2].z, aB2); aB3 = fmaf(B[11], xB[4*K+2].w, aB3); \
    aB0 = fmaf(B[12], xB[4*K+3].x, aB0); aB1 = fmaf(B[13], xB[4*K+3].y, aB1); \
    aB2 = fmaf(B[14], xB[4*K+3].z, aB2); aB3 = fmaf(B[15], xB[4*K+3].w, aB3);

// Same math/order, VMEM-loaded code held as 16 float4 (dims 4N..4N+3 in cN).
#define DO_V4(C, N) \
    vA0 = fmaf(C[0], xA[N].x, vA0); vA1 = fmaf(C[1], xA[N].y, vA1); \
    vA2 = fmaf(C[2], xA[N].z, vA2); vA3 = fmaf(C[3], xA[N].w, vA3); \
    vB0 = fmaf(C[0], xB[N].x, vB0); vB1 = fmaf(C[1], xB[N].y, vB1); \
    vB2 = fmaf(C[2], xB[N].z, vB2); vB3 = fmaf(C[3], xB[N].w, vB3);

// 512 blocks x 256 threads (2 blocks/CU, 2 waves/SIMD). Block owns 128
// queries (2/lane); wave w owns codes [w*256, w*256+256). Per iteration the
// wave processes TWO codes on two independent pipes: even code streamed
// through SGPRs (s_load_dwordx16, self-contained asm), odd code through
// uniform-address VMEM (global_load_dwordx4, 64-lane broadcast coalesce).
// VMEM's vmcnt wait sits after the SMEM FMAs so its latency hides under
// them; sibling wave covers the SMEM wait (max(2C, C+L) = 2C -> VALU-bound).
__global__ __launch_bounds__(256, 2) void vq_main_kernel(const float* __restrict__ x,
                                                         const float* __restrict__ emb,
                                                         float* __restrict__ out,
                                                         float* __restrict__ ws) {
    __shared__ float e2l[NK];        // 4 KB, broadcast-read (wave-uniform addr)
    __shared__ float sm_s[512];
    __shared__ int   sm_c[512];

    const int tid = threadIdx.x;
    const int l   = tid & 63;
    const int w   = tid >> 6;
    const int qbase = blockIdx.x * 128;
    const int qA = qbase + l;
    const int qB = qbase + 64 + l;

    // Per-block |e|^2 for all 1024 codes (4 rows/thread, deterministic).
#pragma unroll
    for (int c = 0; c < 4; ++c) {
        int row = c * 256 + tid;
        const float4* e4 = (const float4*)(emb + (long)row * D);
        float s = 0.f;
#pragma unroll
        for (int i = 0; i < D / 4; ++i) {
            float4 v = e4[i];
            s += v.x * v.x + v.y * v.y + v.z * v.z + v.w * v.w;
        }
        e2l[row] = s;
    }

    // Both queries resident in VGPRs (128 VGPRs).
    float4 xA[16], xB[16];
    const float4* xpA = (const float4*)(x + (long)qA * D);
    const float4* xpB = (const float4*)(x + (long)qB * D);
#pragma unroll
    for (int i = 0; i < 16; ++i) { xA[i] = xpA[i]; xB[i] = xpB[i]; }
    __syncthreads();

    const int code0 = __builtin_amdgcn_readfirstlane(w << 8);  // wave's first code
    const float* eps0 = emb + (long)code0 * D;                 // SMEM stream base

    float bestA = 3.4e38f, bestB = 3.4e38f;
    int idxA = 0, idxB = 0;

#pragma unroll 1
    for (int g = 0; g < 128; ++g) {
        const int cs = code0 + 2 * g;            // even code: SMEM pipe
        const float* ep = eps0 + (2 * g) * D;    // wave-uniform -> SGPR pair
        const float* vp = eps0 + (2 * g + 1) * D; // odd code: VMEM pipe

        // ---- VMEM: issue 16 uniform-address dwordx4 loads (no wait yet) ----
        f32x4v c0, c1, c2, c3, c4, c5, c6, c7, c8, c9, c10, c11, c12, c13, c14, c15;
        asm volatile(
            "global_load_dwordx4 %0, %16, off\n\t"
            "global_load_dwordx4 %1, %16, off offset:16\n\t"
            "global_load_dwordx4 %2, %16, off offset:32\n\t"
            "global_load_dwordx4 %3, %16, off offset:48\n\t"
            "global_load_dwordx4 %4, %16, off offset:64\n\t"
            "global_load_dwordx4 %5, %16, off offset:80\n\t"
            "global_load_dwordx4 %6, %16, off offset:96\n\t"
            "global_load_dwordx4 %7, %16, off offset:112\n\t"
            "global_load_dwordx4 %8, %16, off offset:128\n\t"
            "global_load_dwordx4 %9, %16, off offset:144\n\t"
            "global_load_dwordx4 %10, %16, off offset:160\n\t"
            "global_load_dwordx4 %11, %16, off offset:176\n\t"
            "global_load_dwordx4 %12, %16, off offset:192\n\t"
            "global_load_dwordx4 %13, %16, off offset:208\n\t"
            "global_load_dwordx4 %14, %16, off offset:224\n\t"
            "global_load_dwordx4 %15, %16, off offset:240"
            : "=v"(c0), "=v"(c1), "=v"(c2), "=v"(c3),
              "=v"(c4), "=v"(c5), "=v"(c6), "=v"(c7),
              "=v"(c8), "=v"(c9), "=v"(c10), "=v"(c11),
              "=v"(c12), "=v"(c13), "=v"(c14), "=v"(c15)
            : "v"(vp));

        // ---- SMEM: self-contained load+wait (no in-flight SGPRs escape) ----
        f32x16 b0, b1, b2, b3;
        asm volatile(
            "s_load_dwordx16 %0, %4, 0x0\n\t"
            "s_load_dwordx16 %1, %4, 0x40\n\t"
            "s_load_dwordx16 %2, %4, 0x80\n\t"
            "s_load_dwordx16 %3, %4, 0xC0\n\t"
            "s_waitcnt lgkmcnt(0)"
            : "=s"(b0), "=s"(b1), "=s"(b2), "=s"(b3)
            : "s"(ep));

        // SMEM-code FMAs (hide VMEM latency under these 256 FMAs).
        float aA0 = 0.f, aA1 = 0.f, aA2 = 0.f, aA3 = 0.f;
        float aB0 = 0.f, aB1 = 0.f, aB2 = 0.f, aB3 = 0.f;
        DO_CHUNK(b0, 0)
        DO_CHUNK(b1, 1)
        DO_CHUNK(b2, 2)
        DO_CHUNK(b3, 3)

        // ---- drain VMEM, then its FMAs ----
        asm volatile("s_waitcnt vmcnt(0)"
                     : "+v"(c0), "+v"(c1), "+v"(c2), "+v"(c3),
                       "+v"(c4), "+v"(c5), "+v"(c6), "+v"(c7),
                       "+v"(c8), "+v"(c9), "+v"(c10), "+v"(c11),
                       "+v"(c12), "+v"(c13), "+v"(c14), "+v"(c15));

        float vA0 = 0.f, vA1 = 0.f, vA2 = 0.f, vA3 = 0.f;
        float vB0 = 0.f, vB1 = 0.f, vB2 = 0.f, vB3 = 0.f;
        DO_V4(c0, 0)  DO_V4(c1, 1)  DO_V4(c2, 2)  DO_V4(c3, 3)
        DO_V4(c4, 4)  DO_V4(c5, 5)  DO_V4(c6, 6)  DO_V4(c7, 7)
        DO_V4(c8, 8)  DO_V4(c9, 9)  DO_V4(c10, 10) DO_V4(c11, 11)
        DO_V4(c12, 12) DO_V4(c13, 13) DO_V4(c14, 14) DO_V4(c15, 15)

        // distances + argmin updates, strictly ascending code order (cs, cs+1)
        float e2s = e2l[cs];
        float e2v = e2l[cs + 1];
        float dSA = (aA0 + aA1) + (aA2 + aA3);
        float dSB = (aB0 + aB1) + (aB2 + aB3);
        float dVA = (vA0 + vA1) + (vA2 + vA3);
        float dVB = (vB0 + vB1) + (vB2 + vB3);

        float sSA = 0.5f * e2s - dSA;
        float sSB = 0.5f * e2s - dSB;
        bool lt;
        lt = sSA < bestA; bestA = lt ? sSA : bestA; idxA = lt ? cs : idxA;
        lt = sSB < bestB; bestB = lt ? sSB : bestB; idxB = lt ? cs : idxB;

        float sVA = 0.5f * e2v - dVA;
        float sVB = 0.5f * e2v - dVB;
        lt = sVA < bestA; bestA = lt ? sVA : bestA; idxA = lt ? (cs + 1) : idxA;
        lt = sVB < bestB; bestB = lt ? sVB : bestB; idxB = lt ? (cs + 1) : idxB;
    }

    // Cross-wave merge: ascending wave == ascending code range, strict < keeps
    // the first minimum (numpy argmin tie-break preserved).
    sm_s[w * 128 + l]      = bestA;  sm_c[w * 128 + l]      = idxA;
    sm_s[w * 128 + 64 + l] = bestB;  sm_c[w * 128 + 64 + l] = idxB;
    __syncthreads();

    if (tid < 128) {
        float bs = sm_s[tid];
        int   bc = sm_c[tid];
#pragma unroll
        for (int wv = 1; wv < 4; ++wv) {
            float s = sm_s[wv * 128 + tid];
            int   c = sm_c[wv * 128 + tid];
            if (s < bs) { bs = s; bc = c; }
        }
        const int q = qbase + tid;
        out[IDX_OFF + q] = (float)bc;

        const float4* eb = (const float4*)(emb + (long)bc * D);
        const float4* xq = (const float4*)(x + (long)q * D);
        float4* oq = (float4*)(out + (long)q * D);
        float lsum = 0.f;
#pragma unroll
        for (int i = 0; i < 16; ++i) {
            float4 e = eb[i];
            float4 xx = xq[i];
            oq[i] = e;
            float dx = e.x - xx.x, dy = e.y - xx.y, dz = e.z - xx.z, dw = e.w - xx.w;
            lsum += dx * dx + dy * dy + dz * dz + dw * dw;
        }
        // tid<128 spans waves 0 and 1, both fully active -> 64-lane reduce
#pragma unroll
        for (int o = 32; o > 0; o >>= 1)
            lsum += __shfl_down(lsum, o, 64);
        if ((tid & 63) == 0)
            ws[blockIdx.x * 2 + (tid >> 6)] = lsum;   // raw partial
    }
}

// Tail: reduce 1024 per-block partials -> loss. One wave.
__global__ __launch_bounds__(64) void vq_loss_kernel(const float* __restrict__ ws,
                                                     float* __restrict__ out) {
    const int l = threadIdx.x;
    float s = 0.f;
#pragma unroll
    for (int i = 0; i < 16; ++i) s += ws[l + 64 * i];
#pragma unroll
    for (int o = 32; o > 0; o >>= 1) s += __shfl_down(s, o, 64);
    if (l == 0) out[LOSS_OFF] = s * (0.25f / (float)NELEM);
}

extern "C" void kernel_launch(void* const* d_in, const int* in_sizes, int n_in,
                              void* d_out, int out_size, void* d_ws, size_t ws_size,
                              hipStream_t stream) {
    const float* inputs = (const float*)d_in[0];      // [65536, 64]
    const float* emb    = (const float*)d_in[1];      // [1024, 64]
    float* out = (float*)d_out;
    float* ws  = (float*)d_ws;                        // 1024 partial-loss floats

    vq_main_kernel<<<QTOTAL / 128, 256, 0, stream>>>(inputs, emb, out, ws);
    vq_loss_kernel<<<1, 64, 0, stream>>>(ws, out);
}